// Round 5
// baseline (51.118 us; speedup 1.0000x reference)
//
#include <hip/hip_runtime.h>

// ThetaGammaCLEVRN — element-per-thread, j-split, SGPR weights.
// Math reduction (phase network is dead code; theta amps stay exactly 1):
//   sf[16] = sum_o scene[e,o,:]          (0.1 mean factor folded into Ws)
//   x[j]   = sf @ (0.1*Ws) + bs ; ga[j] = F20(sigmoid(x[j]))  via 512-entry LUT
//   h[j]   = relu(ga @ W1[16:80] + query @ Weff + beff)
//   out    = log_softmax(h @ W2 + b2)
// Weff = Wq @ W1[80:144]; beff = b1 + sum_{k<16} W1[k,:] + bq @ W1[80:144].
//
// R5: weights are read with WAVE-UNIFORM indices straight from global memory
// -> compiler emits s_load into SGPRs (scalar pipe + K$), freeing the DS pipe
// (R4 burned ~1000 ds_read_b128/wave on LDS "broadcasts"). LDS keeps only
// per-lane data: LUT + transposed fp16 activations. Each element's 64 hidden
// units are split across 2 threads (j-halves) -> 512 blocks, 2 blocks/CU.

typedef __fp16 h2_t __attribute__((ext_vector_type(2)));
union H2U { unsigned u; h2_t h; };

__device__ __forceinline__ unsigned pk(float a, float b) {
    H2U v; v.h = __builtin_amdgcn_cvt_pkrtz(a, b);
    return v.u;
}
__device__ __forceinline__ h2_t uh(unsigned x) { H2U v; v.u = x; return v.h; }
__device__ __forceinline__ float dot2(h2_t a, h2_t b, float c) {
#if __has_builtin(__builtin_amdgcn_fdot2)
    return __builtin_amdgcn_fdot2(a, b, c, false);
#else
    return c + (float)a.x * (float)b.x + (float)a.y * (float)b.y;
#endif
}
__device__ __forceinline__ float F20(float g) {
    #pragma unroll
    for (int n = 0; n < 20; ++n) {
        float g2 = g * g;
        g = fmaf(0.01f, g * (1.0f - g2), g);
    }
    return g;
}

// ws layout (fp32 words):
//   0    : Wh   [62*64]  half2(W[2kp][j], W[2kp+1][j]) of stacked [W1g;Weff]
//   3968 : Wsh  [64*8]   half2(0.1*Ws[2dp][j], 0.1*Ws[2dp+1][j]), idx j*8+dp
//   4480 : T2   [512*2]  (F(sig(x_i)), F(sig(x_{i+1}))-F(sig(x_i))), x_i=i/64-4
//   5504 : beff [64]
//   5568 : W2f2 [128]
//   5696 : bs   [64]
//   5760 : b2   [2]      -> total 5762 words
#define CW 5762

__global__ void prep_kernel(const float* __restrict__ Ws,
                            const float* __restrict__ bs,
                            const float* __restrict__ Wq,
                            const float* __restrict__ bq,
                            const float* __restrict__ W1,
                            const float* __restrict__ b1,
                            const float* __restrict__ W2,
                            const float* __restrict__ b2,
                            float* __restrict__ ws) {
    unsigned* wsu = (unsigned*)ws;
    int gid = blockIdx.x * 256 + threadIdx.x;
    if (gid < 3968) {                        // Wh
        int kp = gid >> 6, j = gid & 63;
        float a, b;
        if (kp < 32) {
            a = W1[(16 + 2 * kp) * 64 + j];
            b = W1[(17 + 2 * kp) * 64 + j];
        } else {
            int qd = 2 * (kp - 32);
            float s0 = 0.f, s1 = 0.f;
            #pragma unroll 16
            for (int c = 0; c < 64; ++c) {
                float w = W1[(80 + c) * 64 + j];
                s0 = fmaf(Wq[qd * 64 + c], w, s0);
                s1 = fmaf(Wq[(qd + 1) * 64 + c], w, s1);
            }
            a = s0; b = s1;
        }
        wsu[gid] = pk(a, b);
    } else if (gid >= 4096 && gid < 4608) {  // Wsh
        int w = gid - 4096, j = w >> 3, dp = w & 7;
        wsu[3968 + w] = pk(0.1f * Ws[(2 * dp) * 64 + j],
                           0.1f * Ws[(2 * dp + 1) * 64 + j]);
    } else if (gid >= 5120 && gid < 5632) {  // LUT
        int i = gid - 5120;
        float x0 = (float)i * 0.015625f - 4.0f;
        float x1 = x0 + 0.015625f;
        float F0 = F20(1.0f / (1.0f + expf(-x0)));
        float F1 = F20(1.0f / (1.0f + expf(-x1)));
        ws[4480 + 2 * i]     = F0;
        ws[4480 + 2 * i + 1] = F1 - F0;
    } else if (gid >= 5632 && gid < 5696) {  // beff
        int j = gid - 5632;
        float acc = b1[j];
        #pragma unroll
        for (int k = 0; k < 16; ++k) acc += W1[k * 64 + j];
        #pragma unroll 16
        for (int c = 0; c < 64; ++c)
            acc = fmaf(bq[c], W1[(80 + c) * 64 + j], acc);
        ws[5504 + j] = acc;
    } else if (gid >= 5696 && gid < 5824) {  // W2 copy
        ws[5568 + (gid - 5696)] = W2[gid - 5696];
    } else if (gid >= 5824 && gid < 5888) {  // bs copy
        ws[5696 + (gid - 5824)] = bs[gid - 5824];
    } else if (gid == 5888) {
        ws[5760] = b2[0];
        ws[5761] = b2[1];
    }
}

__global__ __launch_bounds__(256, 2) void fused_kernel(
    const float* __restrict__ scene,   // (B,10,16)
    const float* __restrict__ query,   // (B,60)
    const float* __restrict__ wsbuf,   // CW words, see layout
    float* __restrict__ out)           // (B,2)
{
    __shared__ float    lutS[1024];        // 4 KB  (float2[512])
    __shared__ unsigned sfT2[8 * 129];     // 4.1 KB
    __shared__ unsigned qT2[30 * 129];     // 15.5 KB
    __shared__ float    pl[2 * 128];       // 1 KB upper-half partials

    const int t  = threadIdx.x;
    const int eb = blockIdx.x << 7;        // 128 elements per block

    // ---- stage LUT (per-lane gathers later) ----
    #pragma unroll
    for (int i = 0; i < 4; ++i) lutS[t + (i << 8)] = wsbuf[4480 + t + (i << 8)];

    // ---- stage scene -> sf sums, transposed fp16 pairs ----
    #pragma unroll
    for (int p = 0; p < 2; ++p) {
        const int el = (p << 6) + (t >> 2);
        const int c4 = t & 3;
        const float4* sp = (const float4*)scene + (size_t)(eb + el) * 40 + c4;
        float4 acc = sp[0];
        #pragma unroll
        for (int o = 1; o < 10; ++o) {
            float4 v = sp[o * 4];
            acc.x += v.x; acc.y += v.y; acc.z += v.z; acc.w += v.w;
        }
        sfT2[(2 * c4) * 129 + el]     = pk(acc.x, acc.y);
        sfT2[(2 * c4 + 1) * 129 + el] = pk(acc.z, acc.w);
    }

    // ---- stage query, transposed fp16 pairs (128*15 = 1920 float4) ----
    #pragma unroll
    for (int i = 0; i < 8; ++i) {
        const int q4 = t + (i << 8);
        if (q4 < 1920) {
            const int el = q4 / 15, kq = q4 % 15;
            float4 qv = ((const float4*)query)[(size_t)(eb + el) * 15 + kq];
            qT2[(2 * kq) * 129 + el]     = pk(qv.x, qv.y);
            qT2[(2 * kq + 1) * 129 + el] = pk(qv.z, qv.w);
        }
    }
    __syncthreads();

    // ============ per-thread: element el, hidden half `half` ============
    const int el   = t & 127;
    const int half = t >> 7;               // wave-uniform
    const int j0   = half << 5;            // 32*half

    h2_t sf[8];
    #pragma unroll
    for (int dp = 0; dp < 8; ++dp) sf[dp] = uh(sfT2[dp * 129 + el]);

    float h[32];
    #pragma unroll
    for (int j = 0; j < 32; ++j) h[j] = wsbuf[5504 + j0 + j];   // s_load

    const uint4* Wg = (const uint4*)wsbuf;   // word index / 4
    const float2* T2 = (const float2*)lutS;

    // ---- gamma k-pairs 0..31 (ga computed on the fly via LUT) ----
    #pragma unroll 2
    for (int kp = 0; kp < 32; ++kp) {
        // Wsh rows 2kp,2kp+1 : words 3968+16*kp..+15 -> uint4 992+4*kp..+3
        const uint4 wa = Wg[992 + 4 * kp + 0];
        const uint4 wb = Wg[992 + 4 * kp + 1];
        const uint4 wc = Wg[992 + 4 * kp + 2];
        const uint4 wd = Wg[992 + 4 * kp + 3];
        float x0 = wsbuf[5696 + 2 * kp];
        float x1 = wsbuf[5696 + 2 * kp + 1];
        x0 = dot2(sf[0], uh(wa.x), x0); x0 = dot2(sf[1], uh(wa.y), x0);
        x0 = dot2(sf[2], uh(wa.z), x0); x0 = dot2(sf[3], uh(wa.w), x0);
        x0 = dot2(sf[4], uh(wb.x), x0); x0 = dot2(sf[5], uh(wb.y), x0);
        x0 = dot2(sf[6], uh(wb.z), x0); x0 = dot2(sf[7], uh(wb.w), x0);
        x1 = dot2(sf[0], uh(wc.x), x1); x1 = dot2(sf[1], uh(wc.y), x1);
        x1 = dot2(sf[2], uh(wc.z), x1); x1 = dot2(sf[3], uh(wc.w), x1);
        x1 = dot2(sf[4], uh(wd.x), x1); x1 = dot2(sf[5], uh(wd.y), x1);
        x1 = dot2(sf[6], uh(wd.z), x1); x1 = dot2(sf[7], uh(wd.w), x1);
        float u0 = fminf(fmaxf(fmaf(x0, 64.0f, 256.0f), 0.0f), 511.0f);
        float u1 = fminf(fmaxf(fmaf(x1, 64.0f, 256.0f), 0.0f), 511.0f);
        int   i0 = (int)u0, i1 = (int)u1;
        float2 e0 = T2[i0], e1 = T2[i1];
        float g0 = fmaf(u0 - (float)i0, e0.y, e0.x);
        float g1 = fmaf(u1 - (float)i1, e1.y, e1.x);
        H2U a2u; a2u.u = pk(g0, g1);
        const h2_t a2 = a2u.h;
        // this wave's 32 hidden units: uint4 rows kp*16 + 8*half + jq
        #pragma unroll
        for (int jq = 0; jq < 8; ++jq) {
            uint4 w = Wg[kp * 16 + (half << 3) + jq];   // s_load (uniform)
            h[4 * jq + 0] = dot2(a2, uh(w.x), h[4 * jq + 0]);
            h[4 * jq + 1] = dot2(a2, uh(w.y), h[4 * jq + 1]);
            h[4 * jq + 2] = dot2(a2, uh(w.z), h[4 * jq + 2]);
            h[4 * jq + 3] = dot2(a2, uh(w.w), h[4 * jq + 3]);
        }
    }

    // ---- query k-pairs 0..29 (activation pair per-lane from LDS) ----
    #pragma unroll 2
    for (int kp = 0; kp < 30; ++kp) {
        const h2_t a2 = uh(qT2[kp * 129 + el]);
        #pragma unroll
        for (int jq = 0; jq < 8; ++jq) {
            uint4 w = Wg[(32 + kp) * 16 + (half << 3) + jq];
            h[4 * jq + 0] = dot2(a2, uh(w.x), h[4 * jq + 0]);
            h[4 * jq + 1] = dot2(a2, uh(w.y), h[4 * jq + 1]);
            h[4 * jq + 2] = dot2(a2, uh(w.z), h[4 * jq + 2]);
            h[4 * jq + 3] = dot2(a2, uh(w.w), h[4 * jq + 3]);
        }
    }

    // ---- partial logits over this half's 32 units ----
    float l0 = 0.f, l1 = 0.f;
    #pragma unroll
    for (int j = 0; j < 32; ++j) {
        float hv = fmaxf(h[j], 0.0f);
        float wx = wsbuf[5568 + 2 * (j0 + j)];       // s_load
        float wy = wsbuf[5568 + 2 * (j0 + j) + 1];
        l0 = fmaf(hv, wx, l0);
        l1 = fmaf(hv, wy, l1);
    }

    if (half) { pl[2 * el] = l0; pl[2 * el + 1] = l1; }
    __syncthreads();
    if (!half) {
        l0 += pl[2 * el]     + wsbuf[5760];
        l1 += pl[2 * el + 1] + wsbuf[5761];
        const float mx = fmaxf(l0, l1);
        const float lz = mx + __logf(__expf(l0 - mx) + __expf(l1 - mx));
        float2 o = { l0 - lz, l1 - lz };
        ((float2*)out)[eb + el] = o;
    }
}

extern "C" void kernel_launch(void* const* d_in, const int* in_sizes, int n_in,
                              void* d_out, int out_size, void* d_ws, size_t ws_size,
                              hipStream_t stream) {
    const float* scene = (const float*)d_in[0];
    const float* query = (const float*)d_in[1];
    // d_in[2..5] = theta/gamma phase & freq: provably unused by the output
    const float* Ws = (const float*)d_in[6];
    const float* bs = (const float*)d_in[7];
    const float* Wq = (const float*)d_in[8];
    const float* bq = (const float*)d_in[9];
    const float* W1 = (const float*)d_in[10];
    const float* b1 = (const float*)d_in[11];
    const float* W2 = (const float*)d_in[12];
    const float* b2 = (const float*)d_in[13];
    float* out = (float*)d_out;
    float* ws  = (float*)d_ws;   // needs CW*4 = 23 KB

    const int B = in_sizes[0] / 160;   // 65536
    prep_kernel<<<24, 256, 0, stream>>>(Ws, bs, Wq, bq, W1, b1, W2, b2, ws);
    fused_kernel<<<B / 128, 256, 0, stream>>>(scene, query, ws, out);
}

// Round 6
// 40.528 us; speedup vs baseline: 1.2613x; 1.2613x over previous
//
#include <hip/hip_runtime.h>

// ThetaGammaCLEVRN — element-per-thread, j-split, SGPR weights (R6).
// Math reduction (phase network is dead code; theta amps stay exactly 1):
//   sf[16] = sum_o scene[e,o,:]          (0.1 mean factor folded into Ws)
//   x[j]   = sf @ (0.1*Ws) + bs ; ga[j] = F20(sigmoid(x[j]))  via 512-entry LUT
//   h[j]   = relu(ga @ W1[16:80] + query @ Weff + beff)
//   out    = log_softmax(h @ W2 + b2)
// Weff = Wq @ W1[80:144]; beff = b1 + sum_{k<16} W1[k,:] + bq @ W1[80:144].
//
// R6 fix over R5: `half` was threadIdx-derived -> clang's divergence analysis
// couldn't prove it uniform -> weight reads were per-lane global_load_dwordx4
// (vmcnt-serialized, 79% stall). Now the wave id comes from
// readfirstlane(threadIdx.x)>>6, so half and all weight indices are
// SGPR-derived -> s_load on the scalar pipe + K$ (the correct broadcast path).

typedef __fp16 h2_t __attribute__((ext_vector_type(2)));
union H2U { unsigned u; h2_t h; };

__device__ __forceinline__ unsigned pk(float a, float b) {
    H2U v; v.h = __builtin_amdgcn_cvt_pkrtz(a, b);
    return v.u;
}
__device__ __forceinline__ h2_t uh(unsigned x) { H2U v; v.u = x; return v.h; }
__device__ __forceinline__ float dot2(h2_t a, h2_t b, float c) {
#if __has_builtin(__builtin_amdgcn_fdot2)
    return __builtin_amdgcn_fdot2(a, b, c, false);
#else
    return c + (float)a.x * (float)b.x + (float)a.y * (float)b.y;
#endif
}
__device__ __forceinline__ float F20(float g) {
    #pragma unroll
    for (int n = 0; n < 20; ++n) {
        float g2 = g * g;
        g = fmaf(0.01f, g * (1.0f - g2), g);
    }
    return g;
}

// ws layout (fp32 words):
//   0    : Wh   [62*64]  half2(W[2kp][j], W[2kp+1][j]) of stacked [W1g;Weff]
//   3968 : Wsh  [64*8]   half2(0.1*Ws[2dp][j], 0.1*Ws[2dp+1][j]), idx j*8+dp
//   4480 : T2   [512*2]  (F(sig(x_i)), F(sig(x_{i+1}))-F(sig(x_i))), x_i=i/64-4
//   5504 : beff [64]
//   5568 : W2f2 [128]
//   5696 : bs   [64]
//   5760 : b2   [2]      -> total 5762 words
#define CW 5762

__global__ void prep_kernel(const float* __restrict__ Ws,
                            const float* __restrict__ bs,
                            const float* __restrict__ Wq,
                            const float* __restrict__ bq,
                            const float* __restrict__ W1,
                            const float* __restrict__ b1,
                            const float* __restrict__ W2,
                            const float* __restrict__ b2,
                            float* __restrict__ ws) {
    unsigned* wsu = (unsigned*)ws;
    int gid = blockIdx.x * 256 + threadIdx.x;
    if (gid < 3968) {                        // Wh
        int kp = gid >> 6, j = gid & 63;
        float a, b;
        if (kp < 32) {
            a = W1[(16 + 2 * kp) * 64 + j];
            b = W1[(17 + 2 * kp) * 64 + j];
        } else {
            int qd = 2 * (kp - 32);
            float s0 = 0.f, s1 = 0.f;
            #pragma unroll 16
            for (int c = 0; c < 64; ++c) {
                float w = W1[(80 + c) * 64 + j];
                s0 = fmaf(Wq[qd * 64 + c], w, s0);
                s1 = fmaf(Wq[(qd + 1) * 64 + c], w, s1);
            }
            a = s0; b = s1;
        }
        wsu[gid] = pk(a, b);
    } else if (gid >= 4096 && gid < 4608) {  // Wsh
        int w = gid - 4096, j = w >> 3, dp = w & 7;
        wsu[3968 + w] = pk(0.1f * Ws[(2 * dp) * 64 + j],
                           0.1f * Ws[(2 * dp + 1) * 64 + j]);
    } else if (gid >= 5120 && gid < 5632) {  // LUT
        int i = gid - 5120;
        float x0 = (float)i * 0.015625f - 4.0f;
        float x1 = x0 + 0.015625f;
        float F0 = F20(1.0f / (1.0f + expf(-x0)));
        float F1 = F20(1.0f / (1.0f + expf(-x1)));
        ws[4480 + 2 * i]     = F0;
        ws[4480 + 2 * i + 1] = F1 - F0;
    } else if (gid >= 5632 && gid < 5696) {  // beff
        int j = gid - 5632;
        float acc = b1[j];
        #pragma unroll
        for (int k = 0; k < 16; ++k) acc += W1[k * 64 + j];
        #pragma unroll 16
        for (int c = 0; c < 64; ++c)
            acc = fmaf(bq[c], W1[(80 + c) * 64 + j], acc);
        ws[5504 + j] = acc;
    } else if (gid >= 5696 && gid < 5824) {  // W2 copy
        ws[5568 + (gid - 5696)] = W2[gid - 5696];
    } else if (gid >= 5824 && gid < 5888) {  // bs copy
        ws[5696 + (gid - 5824)] = bs[gid - 5824];
    } else if (gid == 5888) {
        ws[5760] = b2[0];
        ws[5761] = b2[1];
    }
}

__global__ __launch_bounds__(256, 2) void fused_kernel(
    const float* __restrict__ scene,   // (B,10,16)
    const float* __restrict__ query,   // (B,60)
    const float* __restrict__ wsbuf,   // CW words, see layout
    float* __restrict__ out)           // (B,2)
{
    __shared__ float    lutS[1024];        // 4 KB  (float2[512])
    __shared__ unsigned sfT2[8 * 129];     // 4.1 KB
    __shared__ unsigned qT2[30 * 129];     // 15.5 KB
    __shared__ float    pl[2 * 128];       // 1 KB upper-half partials

    const int t  = threadIdx.x;
    const int eb = blockIdx.x << 7;        // 128 elements per block

    // ---- stage LUT (per-lane gathers later) ----
    #pragma unroll
    for (int i = 0; i < 4; ++i) lutS[t + (i << 8)] = wsbuf[4480 + t + (i << 8)];

    // ---- stage scene -> sf sums, transposed fp16 pairs ----
    #pragma unroll
    for (int p = 0; p < 2; ++p) {
        const int el = (p << 6) + (t >> 2);
        const int c4 = t & 3;
        const float4* sp = (const float4*)scene + (size_t)(eb + el) * 40 + c4;
        float4 acc = sp[0];
        #pragma unroll
        for (int o = 1; o < 10; ++o) {
            float4 v = sp[o * 4];
            acc.x += v.x; acc.y += v.y; acc.z += v.z; acc.w += v.w;
        }
        sfT2[(2 * c4) * 129 + el]     = pk(acc.x, acc.y);
        sfT2[(2 * c4 + 1) * 129 + el] = pk(acc.z, acc.w);
    }

    // ---- stage query, transposed fp16 pairs (128*15 = 1920 float4) ----
    #pragma unroll
    for (int i = 0; i < 8; ++i) {
        const int q4 = t + (i << 8);
        if (q4 < 1920) {
            const int el = q4 / 15, kq = q4 % 15;
            float4 qv = ((const float4*)query)[(size_t)(eb + el) * 15 + kq];
            qT2[(2 * kq) * 129 + el]     = pk(qv.x, qv.y);
            qT2[(2 * kq + 1) * 129 + el] = pk(qv.z, qv.w);
        }
    }
    __syncthreads();

    // ============ per-thread: element el, hidden half `half` ============
    // PROVABLY-uniform wave id: readfirstlane -> SGPR -> weight reads become
    // s_load (scalar pipe). Lane-divergent el is re-derived consistently:
    // wave0: half0,el 0-63 | wave1: half0,el 64-127 | wave2/3: half1 same els.
    const int wvu  = __builtin_amdgcn_readfirstlane(threadIdx.x) >> 6;  // 0..3
    const int half = wvu >> 1;                                          // SGPR
    const int el   = (t & 63) | ((wvu & 1) << 6);
    const int j0   = half << 5;            // 32*half

    h2_t sf[8];
    #pragma unroll
    for (int dp = 0; dp < 8; ++dp) sf[dp] = uh(sfT2[dp * 129 + el]);

    float h[32];
    #pragma unroll
    for (int j = 0; j < 32; ++j) h[j] = wsbuf[5504 + j0 + j];   // s_load

    const uint4* Wg = (const uint4*)wsbuf;   // word index / 4
    const float2* T2 = (const float2*)lutS;

    // ---- gamma k-pairs 0..31 (ga computed on the fly via LUT) ----
    #pragma unroll 2
    for (int kp = 0; kp < 32; ++kp) {
        // Wsh rows 2kp,2kp+1 : words 3968+16*kp..+15 -> uint4 992+4*kp..+3
        const uint4 wa = Wg[992 + 4 * kp + 0];
        const uint4 wb = Wg[992 + 4 * kp + 1];
        const uint4 wc = Wg[992 + 4 * kp + 2];
        const uint4 wd = Wg[992 + 4 * kp + 3];
        float x0 = wsbuf[5696 + 2 * kp];
        float x1 = wsbuf[5696 + 2 * kp + 1];
        x0 = dot2(sf[0], uh(wa.x), x0); x0 = dot2(sf[1], uh(wa.y), x0);
        x0 = dot2(sf[2], uh(wa.z), x0); x0 = dot2(sf[3], uh(wa.w), x0);
        x0 = dot2(sf[4], uh(wb.x), x0); x0 = dot2(sf[5], uh(wb.y), x0);
        x0 = dot2(sf[6], uh(wb.z), x0); x0 = dot2(sf[7], uh(wb.w), x0);
        x1 = dot2(sf[0], uh(wc.x), x1); x1 = dot2(sf[1], uh(wc.y), x1);
        x1 = dot2(sf[2], uh(wc.z), x1); x1 = dot2(sf[3], uh(wc.w), x1);
        x1 = dot2(sf[4], uh(wd.x), x1); x1 = dot2(sf[5], uh(wd.y), x1);
        x1 = dot2(sf[6], uh(wd.z), x1); x1 = dot2(sf[7], uh(wd.w), x1);
        float u0 = fminf(fmaxf(fmaf(x0, 64.0f, 256.0f), 0.0f), 511.0f);
        float u1 = fminf(fmaxf(fmaf(x1, 64.0f, 256.0f), 0.0f), 511.0f);
        int   i0 = (int)u0, i1 = (int)u1;
        float2 e0 = T2[i0], e1 = T2[i1];
        float g0 = fmaf(u0 - (float)i0, e0.y, e0.x);
        float g1 = fmaf(u1 - (float)i1, e1.y, e1.x);
        H2U a2u; a2u.u = pk(g0, g1);
        const h2_t a2 = a2u.h;
        // this wave's 32 hidden units: uint4 rows kp*16 + 8*half + jq
        #pragma unroll
        for (int jq = 0; jq < 8; ++jq) {
            uint4 w = Wg[kp * 16 + (half << 3) + jq];   // s_load (uniform)
            h[4 * jq + 0] = dot2(a2, uh(w.x), h[4 * jq + 0]);
            h[4 * jq + 1] = dot2(a2, uh(w.y), h[4 * jq + 1]);
            h[4 * jq + 2] = dot2(a2, uh(w.z), h[4 * jq + 2]);
            h[4 * jq + 3] = dot2(a2, uh(w.w), h[4 * jq + 3]);
        }
    }

    // ---- query k-pairs 0..29 (activation pair per-lane from LDS) ----
    #pragma unroll 2
    for (int kp = 0; kp < 30; ++kp) {
        const h2_t a2 = uh(qT2[kp * 129 + el]);
        #pragma unroll
        for (int jq = 0; jq < 8; ++jq) {
            uint4 w = Wg[(32 + kp) * 16 + (half << 3) + jq];
            h[4 * jq + 0] = dot2(a2, uh(w.x), h[4 * jq + 0]);
            h[4 * jq + 1] = dot2(a2, uh(w.y), h[4 * jq + 1]);
            h[4 * jq + 2] = dot2(a2, uh(w.z), h[4 * jq + 2]);
            h[4 * jq + 3] = dot2(a2, uh(w.w), h[4 * jq + 3]);
        }
    }

    // ---- partial logits over this half's 32 units ----
    float l0 = 0.f, l1 = 0.f;
    #pragma unroll
    for (int j = 0; j < 32; ++j) {
        float hv = fmaxf(h[j], 0.0f);
        float wx = wsbuf[5568 + 2 * (j0 + j)];       // s_load
        float wy = wsbuf[5568 + 2 * (j0 + j) + 1];
        l0 = fmaf(hv, wx, l0);
        l1 = fmaf(hv, wy, l1);
    }

    if (half) { pl[2 * el] = l0; pl[2 * el + 1] = l1; }
    __syncthreads();
    if (!half) {
        l0 += pl[2 * el]     + wsbuf[5760];
        l1 += pl[2 * el + 1] + wsbuf[5761];
        const float mx = fmaxf(l0, l1);
        const float lz = mx + __logf(__expf(l0 - mx) + __expf(l1 - mx));
        float2 o = { l0 - lz, l1 - lz };
        ((float2*)out)[eb + el] = o;
    }
}

extern "C" void kernel_launch(void* const* d_in, const int* in_sizes, int n_in,
                              void* d_out, int out_size, void* d_ws, size_t ws_size,
                              hipStream_t stream) {
    const float* scene = (const float*)d_in[0];
    const float* query = (const float*)d_in[1];
    // d_in[2..5] = theta/gamma phase & freq: provably unused by the output
    const float* Ws = (const float*)d_in[6];
    const float* bs = (const float*)d_in[7];
    const float* Wq = (const float*)d_in[8];
    const float* bq = (const float*)d_in[9];
    const float* W1 = (const float*)d_in[10];
    const float* b1 = (const float*)d_in[11];
    const float* W2 = (const float*)d_in[12];
    const float* b2 = (const float*)d_in[13];
    float* out = (float*)d_out;
    float* ws  = (float*)d_ws;   // needs CW*4 = 23 KB

    const int B = in_sizes[0] / 160;   // 65536
    prep_kernel<<<24, 256, 0, stream>>>(Ws, bs, Wq, bq, W1, b1, W2, b2, ws);
    fused_kernel<<<B / 128, 256, 0, stream>>>(scene, query, ws, out);
}

// Round 7
// 27.098 us; speedup vs baseline: 1.8864x; 1.4956x over previous
//
#include <hip/hip_runtime.h>

// ThetaGammaCLEVRN — MFMA formulation (R7).
// Math reduction (phase network dead; theta amps == 1):
//   sf[16] = sum_o scene[e,o,:]
//   x[g]   = sf@(0.1*Ws) + bs ; ga[g] = F20(sigmoid(x)) via 512-entry LUT
//   h      = relu(W @ act), W = [W1g | Weff | beff] (64x125), act = [ga;q;1]
//   out    = log_softmax(h @ W2 + b2)
// H(64xB) = W·A runs on the MATRIX pipe: mfma_f32_16x16x32_f16, K=128 (pad).
// Per block: 64 elements, 4 waves; wave owns 16 els (one MFMA N-tile),
// 4 j-tiles x 4 k-chunks = 16 MFMAs. W in LDS, 16B-chunk XOR-swizzled ->
// conflict-free ds_read_b128 A-frags. Activations transposed fp16 in LDS.

typedef __fp16 h2_t  __attribute__((ext_vector_type(2)));
typedef __fp16 f16x8 __attribute__((ext_vector_type(8)));
typedef float  f32x4 __attribute__((ext_vector_type(4)));
typedef unsigned u32x4 __attribute__((ext_vector_type(4)));

union H2U { unsigned u; h2_t h; };
union F8  { u32x4 u; f16x8 h; };

__device__ __forceinline__ unsigned pk(float a, float b) {
    H2U v; v.h = __builtin_amdgcn_cvt_pkrtz(a, b);
    return v.u;
}
__device__ __forceinline__ h2_t uh(unsigned x) { H2U v; v.u = x; return v.h; }
__device__ __forceinline__ float dot2(h2_t a, h2_t b, float c) {
    return __builtin_amdgcn_fdot2(a, b, c, false);
}
__device__ __forceinline__ float F20(float g) {
    #pragma unroll
    for (int n = 0; n < 20; ++n) {
        float g2 = g * g;
        g = fmaf(0.01f, g * (1.0f - g2), g);
    }
    return g;
}

// ws layout (u32/f32 words):
//   0    : Wh   [64][64]  fp16 pairs: row j, pair p -> (Wstack[2p][j], Wstack[2p+1][j])
//                         Wstack[k][j]: k<64 = W1[16+k][j]; k<124 = Weff[k-64][j];
//                         k==124 = beff[j]; else 0
//   4096 : ws2T [8][64]   fp16 pairs (0.1*Ws[2dp][g], 0.1*Ws[2dp+1][g])
//   4608 : LUT  [512]x2   (F(x_i), F(x_{i+1})-F(x_i)), x_i = i/64 - 4
//   5632 : bs   [64] f32
//   5696 : w2   [64] float2 (W2 row-major)
//   5824 : b2   [2]  f32        -> 5826 words total
#define NW 5826

__global__ void prep_kernel(const float* __restrict__ Ws,
                            const float* __restrict__ bs,
                            const float* __restrict__ Wq,
                            const float* __restrict__ bq,
                            const float* __restrict__ W1,
                            const float* __restrict__ b1,
                            const float* __restrict__ W2,
                            const float* __restrict__ b2,
                            float* __restrict__ ws) {
    unsigned* wsu = (unsigned*)ws;
    int gid = blockIdx.x * 256 + threadIdx.x;
    if (gid < 4096) {                         // Wh pairs
        int j = gid >> 6, p = gid & 63;
        int k0 = 2 * p;
        float va = 0.f, vb = 0.f;
        if (p < 32) {
            va = W1[(16 + k0) * 64 + j];
            vb = W1[(17 + k0) * 64 + j];
        } else if (p < 62) {                  // Weff dims d0,d0+1
            int d0 = k0 - 64;
            float s0 = 0.f, s1 = 0.f;
            #pragma unroll 16
            for (int c = 0; c < 64; ++c) {
                float w = W1[(80 + c) * 64 + j];
                s0 = fmaf(Wq[d0 * 64 + c], w, s0);
                s1 = fmaf(Wq[(d0 + 1) * 64 + c], w, s1);
            }
            va = s0; vb = s1;
        } else if (p == 62) {                 // k=124: beff ; k=125: 0
            float acc = b1[j];
            #pragma unroll
            for (int r = 0; r < 16; ++r) acc += W1[r * 64 + j];
            #pragma unroll 16
            for (int c = 0; c < 64; ++c)
                acc = fmaf(bq[c], W1[(80 + c) * 64 + j], acc);
            va = acc; vb = 0.f;
        }
        wsu[gid] = pk(va, vb);
    } else if (gid < 4608) {                  // ws2T
        int w = gid - 4096, dp = w >> 6, g = w & 63;
        wsu[gid] = pk(0.1f * Ws[(2 * dp) * 64 + g],
                      0.1f * Ws[(2 * dp + 1) * 64 + g]);
    } else if (gid < 5632) {                  // LUT
        int li = gid - 4608, i = li >> 1;
        float x0 = (float)i * 0.015625f - 4.0f;
        float F0 = F20(1.0f / (1.0f + expf(-x0)));
        if (li & 1) {
            float F1 = F20(1.0f / (1.0f + expf(-(x0 + 0.015625f))));
            ws[gid] = F1 - F0;
        } else {
            ws[gid] = F0;
        }
    } else if (gid < 5696) {                  // bs
        ws[gid] = bs[gid - 5632];
    } else if (gid < 5824) {                  // W2 flat copy
        ws[gid] = W2[gid - 5696];
    } else if (gid < 5826) {
        ws[gid] = b2[gid - 5824];
    }
}

// LDS word offsets
#define W0o  0
#define WS2o 4096
#define LUTo 4608
#define BSo  5632
#define W2o  5696
#define SFTo 5824          // [8][64]
#define QTo  6336          // [32][72]
#define QP   72
#define LDSW (QTo + 32 * QP)   // 8640 words = 34.6 KB

__global__ __launch_bounds__(256, 2) void fused_kernel(
    const float* __restrict__ scene,   // (B,10,16)
    const float* __restrict__ query,   // (B,60)
    const float* __restrict__ wsbuf,   // NW words
    float* __restrict__ out)           // (B,2)
{
    __shared__ unsigned lds[LDSW];
    const int t  = threadIdx.x;
    const int eb = blockIdx.x << 6;        // 64 elements per block
    const unsigned* wsu = (const unsigned*)wsbuf;

    // ---- stage W with 16B-chunk XOR swizzle: chunk' = chunk ^ (j&7) ----
    #pragma unroll
    for (int i = 0; i < 16; ++i) {
        int widx = t + (i << 8);                  // j*64 + w
        int j7 = (widx >> 6) & 7;
        lds[widx] = wsu[widx ^ (j7 << 2)];
    }
    // ---- constants, linear ----
    #pragma unroll
    for (int i = 0; i < 7; ++i) {
        int idx = 4096 + t + (i << 8);
        if (idx < 5824) lds[idx] = wsu[idx];
    }
    // ---- scene: object-sum -> transposed fp16 pairs sfT2[8][64] ----
    {
        const int sel = t >> 2, q4 = t & 3;
        const float4* sp = (const float4*)scene + (size_t)(eb + sel) * 40 + q4;
        float4 a = sp[0];
        #pragma unroll
        for (int o = 1; o < 10; ++o) {
            float4 v = sp[4 * o];
            a.x += v.x; a.y += v.y; a.z += v.z; a.w += v.w;
        }
        lds[SFTo + ((q4 << 1) + 0) * 64 + sel] = pk(a.x, a.y);
        lds[SFTo + ((q4 << 1) + 1) * 64 + sel] = pk(a.z, a.w);
    }
    // ---- query: transposed fp16 pairs qT2[32][72]; rows 30=(1,0), 31=0 ----
    #pragma unroll
    for (int i = 0; i < 4; ++i) {
        int idx = t + (i << 8);
        if (idx < 960) {
            int qel = idx / 15, kq = idx - qel * 15;
            float4 qv = ((const float4*)query)[(size_t)(eb + qel) * 15 + kq];
            lds[QTo + (2 * kq + 0) * QP + qel] = pk(qv.x, qv.y);
            lds[QTo + (2 * kq + 1) * QP + qel] = pk(qv.z, qv.w);
        }
    }
    if (t < 64)       lds[QTo + 30 * QP + t]        = pk(1.0f, 0.0f);
    else if (t < 128) lds[QTo + 31 * QP + (t - 64)] = 0u;

    __syncthreads();

    // ============ compute: wave owns 16 elements (one MFMA N-tile) ========
    const int lane = t & 63;
    const int kb   = lane >> 4;                    // k-group 0..3
    const int elb  = ((t >> 6) << 4) | (lane & 15);

    unsigned sf2[8];
    #pragma unroll
    for (int dp = 0; dp < 8; ++dp) sf2[dp] = lds[SFTo + dp * 64 + elb];

    F8 bfrag[4];
    // ---- gamma B-frags c=0,1: x on VALU dot2, then LUT, pack fp16 ----
    #pragma unroll
    for (int c = 0; c < 2; ++c) {
        float g[8];
        #pragma unroll
        for (int s = 0; s < 2; ++s) {
            unsigned wqa[8][4];
            #pragma unroll
            for (int dp = 0; dp < 8; ++dp) {
                u32x4 w = *(const u32x4*)&lds[WS2o + dp * 64 + (c << 5) + (kb << 3) + (s << 2)];
                wqa[dp][0] = w[0]; wqa[dp][1] = w[1]; wqa[dp][2] = w[2]; wqa[dp][3] = w[3];
            }
            #pragma unroll
            for (int i2 = 0; i2 < 4; ++i2) {
                float x = __uint_as_float(lds[BSo + (c << 5) + (kb << 3) + (s << 2) + i2]);
                #pragma unroll
                for (int dp = 0; dp < 8; ++dp)
                    x = dot2(uh(sf2[dp]), uh(wqa[dp][i2]), x);
                float u = fminf(fmaxf(fmaf(x, 64.0f, 256.0f), 0.0f), 511.0f);
                int   i0 = (int)u;
                float2 e = *(const float2*)&lds[LUTo + (i0 << 1)];
                g[(s << 2) + i2] = fmaf(u - (float)i0, e.y, e.x);
            }
        }
        F8 f;
        f.u[0] = pk(g[0], g[1]); f.u[1] = pk(g[2], g[3]);
        f.u[2] = pk(g[4], g[5]); f.u[3] = pk(g[6], g[7]);
        bfrag[c] = f;
    }
    // ---- query B-frags c=2,3 (includes the const-1 beff column) ----
    #pragma unroll
    for (int c2 = 0; c2 < 2; ++c2) {
        F8 f;
        #pragma unroll
        for (int r = 0; r < 4; ++r)
            f.u[r] = lds[QTo + ((kb << 2) + r + (c2 << 4)) * QP + elb];
        bfrag[2 + c2] = f;
    }

    // ---- MFMA: 4 j-tiles x 4 k-chunks; fused epilogue per j-tile ----
    float l0 = 0.f, l1 = 0.f;
    #pragma unroll
    for (int jt = 0; jt < 4; ++jt) {
        f32x4 acc = {0.f, 0.f, 0.f, 0.f};
        const int j = (jt << 4) | (lane & 15);     // A-frag row
        #pragma unroll
        for (int c = 0; c < 4; ++c) {
            const int ch = ((c << 2) | kb) ^ (j & 7);
            F8 a;
            a.u = *(const u32x4*)&lds[W0o + (j << 6) + (ch << 2)];
            acc = __builtin_amdgcn_mfma_f32_16x16x32_f16(a.h, bfrag[c].h, acc, 0, 0, 0);
        }
        #pragma unroll
        for (int r = 0; r < 4; ++r) {
            const int jr = (jt << 4) + (kb << 2) + r;   // D row of this lane
            float hv = fmaxf(acc[r], 0.f);
            float2 wv = *(const float2*)&lds[W2o + (jr << 1)];
            l0 = fmaf(hv, wv.x, l0);
            l1 = fmaf(hv, wv.y, l1);
        }
    }
    // ---- reduce over k-groups, log_softmax, store ----
    l0 += __shfl_xor(l0, 16); l0 += __shfl_xor(l0, 32);
    l1 += __shfl_xor(l1, 16); l1 += __shfl_xor(l1, 32);
    l0 += wsbuf[5824]; l1 += wsbuf[5825];
    if (lane < 16) {
        const float mx = fmaxf(l0, l1);
        const float lz = mx + __logf(__expf(l0 - mx) + __expf(l1 - mx));
        float2 o = { l0 - lz, l1 - lz };
        ((float2*)out)[eb + elb] = o;
    }
}

extern "C" void kernel_launch(void* const* d_in, const int* in_sizes, int n_in,
                              void* d_out, int out_size, void* d_ws, size_t ws_size,
                              hipStream_t stream) {
    const float* scene = (const float*)d_in[0];
    const float* query = (const float*)d_in[1];
    // d_in[2..5] = theta/gamma phase & freq: provably unused by the output
    const float* Ws = (const float*)d_in[6];
    const float* bs = (const float*)d_in[7];
    const float* Wq = (const float*)d_in[8];
    const float* bq = (const float*)d_in[9];
    const float* W1 = (const float*)d_in[10];
    const float* b1 = (const float*)d_in[11];
    const float* W2 = (const float*)d_in[12];
    const float* b2 = (const float*)d_in[13];
    float* out = (float*)d_out;
    float* ws  = (float*)d_ws;   // needs NW*4 = 23.3 KB

    const int B = in_sizes[0] / 160;   // 65536
    prep_kernel<<<23, 256, 0, stream>>>(Ws, bs, Wq, bq, W1, b1, W2, b2, ws);
    fused_kernel<<<B / 64, 256, 0, stream>>>(scene, query, ws, out);
}

// Round 8
// 26.011 us; speedup vs baseline: 1.9652x; 1.0418x over previous
//
#include <hip/hip_runtime.h>

// ThetaGammaCLEVRN — MFMA + pipelined staging (R8).
// Math reduction (phase network dead; theta amps == 1):
//   sf[16] = sum_o scene[e,o,:]
//   x[g]   = sf@(0.1*Ws) + bs ; ga[g] = F20(sigmoid(x)) via 512-entry LUT
//   h      = relu(W @ act), W = [W1g | Weff | beff] (64x125), act = [ga;q;1]
//   out    = log_softmax(h @ W2 + b2)
// R8 over R7: (a) 128 els/block in 2 groups -> const staging amortized 2x;
// (b) consts staged with async global_load_lds (16B), W-swizzle applied to
// the GLOBAL source address (LDS linear — required by gload_lds semantics);
// (c) group-1 activation loads issued before group-0 compute (T14 split).

typedef __fp16 h2_t  __attribute__((ext_vector_type(2)));
typedef __fp16 f16x8 __attribute__((ext_vector_type(8)));
typedef float  f32x4 __attribute__((ext_vector_type(4)));
typedef unsigned u32x4 __attribute__((ext_vector_type(4)));

union H2U { unsigned u; h2_t h; };
union F8  { u32x4 u; f16x8 h; };

__device__ __forceinline__ unsigned pk(float a, float b) {
    H2U v; v.h = __builtin_amdgcn_cvt_pkrtz(a, b);
    return v.u;
}
__device__ __forceinline__ h2_t uh(unsigned x) { H2U v; v.u = x; return v.h; }
__device__ __forceinline__ float dot2(h2_t a, h2_t b, float c) {
    return __builtin_amdgcn_fdot2(a, b, c, false);
}
__device__ __forceinline__ float F20(float g) {
    #pragma unroll
    for (int n = 0; n < 20; ++n) {
        float g2 = g * g;
        g = fmaf(0.01f, g * (1.0f - g2), g);
    }
    return g;
}

// ws layout (u32/f32 words):
//   0    : Wh   [64][64] fp16 pairs, row j: (Wstack[2p][j], Wstack[2p+1][j])
//   4096 : ws2T [8][64]  fp16 pairs (0.1*Ws[2dp][g], 0.1*Ws[2dp+1][g])
//   4608 : LUT  [512]x2  (F(x_i), F(x_{i+1})-F(x_i)), x_i = i/64 - 4
//   5632 : bs   [64] f32
//   5696 : w2   [128] f32 (W2 row-major)
//   5824 : b2   [2] f32 ; pad zeros to 5888
#define NWP 5888

__global__ void prep_kernel(const float* __restrict__ Ws,
                            const float* __restrict__ bs,
                            const float* __restrict__ Wq,
                            const float* __restrict__ bq,
                            const float* __restrict__ W1,
                            const float* __restrict__ b1,
                            const float* __restrict__ W2,
                            const float* __restrict__ b2,
                            float* __restrict__ ws) {
    unsigned* wsu = (unsigned*)ws;
    int gid = blockIdx.x * 256 + threadIdx.x;
    if (gid < 4096) {                         // Wh pairs
        int j = gid >> 6, p = gid & 63;
        int k0 = 2 * p;
        float va = 0.f, vb = 0.f;
        if (p < 32) {
            va = W1[(16 + k0) * 64 + j];
            vb = W1[(17 + k0) * 64 + j];
        } else if (p < 62) {                  // Weff dims d0,d0+1
            int d0 = k0 - 64;
            float s0 = 0.f, s1 = 0.f;
            #pragma unroll 16
            for (int c = 0; c < 64; ++c) {
                float w = W1[(80 + c) * 64 + j];
                s0 = fmaf(Wq[d0 * 64 + c], w, s0);
                s1 = fmaf(Wq[(d0 + 1) * 64 + c], w, s1);
            }
            va = s0; vb = s1;
        } else if (p == 62) {                 // k=124: beff ; k=125: 0
            float acc = b1[j];
            #pragma unroll
            for (int r = 0; r < 16; ++r) acc += W1[r * 64 + j];
            #pragma unroll 16
            for (int c = 0; c < 64; ++c)
                acc = fmaf(bq[c], W1[(80 + c) * 64 + j], acc);
            va = acc; vb = 0.f;
        }
        wsu[gid] = pk(va, vb);
    } else if (gid < 4608) {                  // ws2T
        int w = gid - 4096, dp = w >> 6, g = w & 63;
        wsu[gid] = pk(0.1f * Ws[(2 * dp) * 64 + g],
                      0.1f * Ws[(2 * dp + 1) * 64 + g]);
    } else if (gid < 5632) {                  // LUT
        int li = gid - 4608, i = li >> 1;
        float x0 = (float)i * 0.015625f - 4.0f;
        float F0 = F20(1.0f / (1.0f + expf(-x0)));
        if (li & 1) {
            float F1 = F20(1.0f / (1.0f + expf(-(x0 + 0.015625f))));
            ws[gid] = F1 - F0;
        } else {
            ws[gid] = F0;
        }
    } else if (gid < 5696) {                  // bs
        ws[gid] = bs[gid - 5632];
    } else if (gid < 5824) {                  // W2 flat copy
        ws[gid] = W2[gid - 5696];
    } else if (gid < NWP) {
        ws[gid] = (gid == 5824) ? b2[0] : (gid == 5825) ? b2[1] : 0.f;
    }
}

// LDS word offsets (const block)
#define W0o  0
#define WS2o 4096
#define LUTo 4608
#define BSo  5632
#define W2o  5696
// per-group activation buffer: sfT[8][64] at 0, qT[32][72] at 512
#define QP   72
#define ACTW 2816

__global__ __launch_bounds__(256, 2) void fused_kernel(
    const float* __restrict__ scene,   // (B,10,16)
    const float* __restrict__ query,   // (B,60)
    const float* __restrict__ wsbuf,   // NWP words
    float* __restrict__ out)           // (B,2)
{
    __shared__ unsigned lds[NWP];          // 23.0 KB constants
    __shared__ unsigned actS[2][ACTW];     // 22.5 KB activations (2 groups)

    const int t    = threadIdx.x;
    const int lane = t & 63;
    const int wv   = __builtin_amdgcn_readfirstlane(t) >> 6;   // SGPR wave id
    const int eb   = blockIdx.x << 7;      // 128 elements per block
    const unsigned* wsu = (const unsigned*)wsbuf;

    // ---- 1) async const staging: 23 chunks x 1 KB, swizzled SOURCE ----
    #pragma unroll
    for (int i = 0; i < 6; ++i) {
        const int chunk = wv * 6 + i;
        if (chunk < 23) {
            const int widx = (chunk << 8) | (lane << 2);
            const int src  = (widx < 4096) ? (widx ^ (((widx >> 6) & 7) << 2))
                                           : widx;
            __builtin_amdgcn_global_load_lds(
                (const __attribute__((address_space(1))) unsigned*)(wsu + src),
                (__attribute__((address_space(3))) unsigned*)&lds[chunk << 8],
                16, 0, 0);
        }
    }

    const int sel = t >> 2, q4 = t & 3;
    // ---- 2) group-0 scene: object-sum -> transposed fp16 pairs ----
    {
        const float4* sp = (const float4*)scene + (size_t)(eb + sel) * 40 + q4;
        float4 a = sp[0];
        #pragma unroll
        for (int o = 1; o < 10; ++o) {
            float4 v = sp[4 * o];
            a.x += v.x; a.y += v.y; a.z += v.z; a.w += v.w;
        }
        actS[0][((q4 << 1) + 0) * 64 + sel] = pk(a.x, a.y);
        actS[0][((q4 << 1) + 1) * 64 + sel] = pk(a.z, a.w);
    }
    // ---- 3) group-0 query -> transposed fp16 pairs ----
    #pragma unroll
    for (int i = 0; i < 4; ++i) {
        const int idx = t + (i << 8);
        if (idx < 960) {
            const int qel = idx / 15, kq = idx - qel * 15;
            float4 qv = ((const float4*)query)[(size_t)(eb + qel) * 15 + kq];
            actS[0][512 + (2 * kq + 0) * QP + qel] = pk(qv.x, qv.y);
            actS[0][512 + (2 * kq + 1) * QP + qel] = pk(qv.z, qv.w);
        }
    }
    // ---- 4) pad rows (k=124 const-1 / k=125..127 zero) for both groups ----
    if (t < 64) {
        actS[0][512 + 30 * QP + t] = pk(1.0f, 0.0f);
        actS[1][512 + 30 * QP + t] = pk(1.0f, 0.0f);
    } else if (t < 128) {
        actS[0][512 + 31 * QP + (t - 64)] = 0u;
        actS[1][512 + 31 * QP + (t - 64)] = 0u;
    }
    __syncthreads();   // consts + act0 ready (drains gload_lds too)

    // ---- 5) issue group-1 loads (consumed after compute-0) ----
    float4 sv[10];
    {
        const float4* sp1 = (const float4*)scene + (size_t)(eb + 64 + sel) * 40 + q4;
        #pragma unroll
        for (int o = 0; o < 10; ++o) sv[o] = sp1[4 * o];
    }
    float4 qv1[4];
    #pragma unroll
    for (int i = 0; i < 4; ++i) {
        const int idx = t + (i << 8);
        if (idx < 960) {
            const int qel = idx / 15, kq = idx - qel * 15;
            qv1[i] = ((const float4*)query)[(size_t)(eb + 64 + qel) * 15 + kq];
        }
    }

    // ============ compute core (identical math to R7) ============
    const int kb  = lane >> 4;
    const int elb = ((t >> 6) << 4) | (lane & 15);

    auto computeGroup = [&](const unsigned* acts, int ebase) {
        unsigned sf2[8];
        #pragma unroll
        for (int dp = 0; dp < 8; ++dp) sf2[dp] = acts[dp * 64 + elb];

        F8 bfrag[4];
        #pragma unroll
        for (int c = 0; c < 2; ++c) {
            float g[8];
            #pragma unroll
            for (int s = 0; s < 2; ++s) {
                unsigned wqa[8][4];
                #pragma unroll
                for (int dp = 0; dp < 8; ++dp) {
                    u32x4 w = *(const u32x4*)&lds[WS2o + dp * 64 + (c << 5) + (kb << 3) + (s << 2)];
                    wqa[dp][0] = w[0]; wqa[dp][1] = w[1];
                    wqa[dp][2] = w[2]; wqa[dp][3] = w[3];
                }
                #pragma unroll
                for (int i2 = 0; i2 < 4; ++i2) {
                    float x = __uint_as_float(lds[BSo + (c << 5) + (kb << 3) + (s << 2) + i2]);
                    #pragma unroll
                    for (int dp = 0; dp < 8; ++dp)
                        x = dot2(uh(sf2[dp]), uh(wqa[dp][i2]), x);
                    float u = fminf(fmaxf(fmaf(x, 64.0f, 256.0f), 0.0f), 511.0f);
                    int   i0 = (int)u;
                    float2 e = *(const float2*)&lds[LUTo + (i0 << 1)];
                    g[(s << 2) + i2] = fmaf(u - (float)i0, e.y, e.x);
                }
            }
            F8 f;
            f.u[0] = pk(g[0], g[1]); f.u[1] = pk(g[2], g[3]);
            f.u[2] = pk(g[4], g[5]); f.u[3] = pk(g[6], g[7]);
            bfrag[c] = f;
        }
        #pragma unroll
        for (int c2 = 0; c2 < 2; ++c2) {
            F8 f;
            #pragma unroll
            for (int r = 0; r < 4; ++r)
                f.u[r] = acts[512 + ((kb << 2) + r + (c2 << 4)) * QP + elb];
            bfrag[2 + c2] = f;
        }

        float l0 = 0.f, l1 = 0.f;
        #pragma unroll
        for (int jt = 0; jt < 4; ++jt) {
            f32x4 acc = {0.f, 0.f, 0.f, 0.f};
            const int j = (jt << 4) | (lane & 15);
            #pragma unroll
            for (int c = 0; c < 4; ++c) {
                const int ch = ((c << 2) | kb) ^ (j & 7);
                F8 a;
                a.u = *(const u32x4*)&lds[W0o + (j << 6) + (ch << 2)];
                acc = __builtin_amdgcn_mfma_f32_16x16x32_f16(a.h, bfrag[c].h, acc, 0, 0, 0);
            }
            #pragma unroll
            for (int r = 0; r < 4; ++r) {
                const int jr = (jt << 4) + (kb << 2) + r;
                float hv = fmaxf(acc[r], 0.f);
                float2 wv2 = *(const float2*)&lds[W2o + (jr << 1)];
                l0 = fmaf(hv, wv2.x, l0);
                l1 = fmaf(hv, wv2.y, l1);
            }
        }
        l0 += __shfl_xor(l0, 16); l0 += __shfl_xor(l0, 32);
        l1 += __shfl_xor(l1, 16); l1 += __shfl_xor(l1, 32);
        l0 += wsbuf[5824]; l1 += wsbuf[5825];
        if (lane < 16) {
            const float mx = fmaxf(l0, l1);
            const float lz = mx + __logf(__expf(l0 - mx) + __expf(l1 - mx));
            float2 o = { l0 - lz, l1 - lz };
            ((float2*)out)[ebase + elb] = o;
        }
    };

    // ---- 6) compute group 0 (group-1 loads in flight) ----
    computeGroup(actS[0], eb);

    // ---- 7) finish group-1 staging ----
    {
        float4 a = sv[0];
        #pragma unroll
        for (int o = 1; o < 10; ++o) {
            a.x += sv[o].x; a.y += sv[o].y; a.z += sv[o].z; a.w += sv[o].w;
        }
        actS[1][((q4 << 1) + 0) * 64 + sel] = pk(a.x, a.y);
        actS[1][((q4 << 1) + 1) * 64 + sel] = pk(a.z, a.w);
    }
    #pragma unroll
    for (int i = 0; i < 4; ++i) {
        const int idx = t + (i << 8);
        if (idx < 960) {
            const int qel = idx / 15, kq = idx - qel * 15;
            actS[1][512 + (2 * kq + 0) * QP + qel] = pk(qv1[i].x, qv1[i].y);
            actS[1][512 + (2 * kq + 1) * QP + qel] = pk(qv1[i].z, qv1[i].w);
        }
    }
    __syncthreads();

    // ---- 8) compute group 1 ----
    computeGroup(actS[1], eb + 64);
}

extern "C" void kernel_launch(void* const* d_in, const int* in_sizes, int n_in,
                              void* d_out, int out_size, void* d_ws, size_t ws_size,
                              hipStream_t stream) {
    const float* scene = (const float*)d_in[0];
    const float* query = (const float*)d_in[1];
    // d_in[2..5] = theta/gamma phase & freq: provably unused by the output
    const float* Ws = (const float*)d_in[6];
    const float* bs = (const float*)d_in[7];
    const float* Wq = (const float*)d_in[8];
    const float* bq = (const float*)d_in[9];
    const float* W1 = (const float*)d_in[10];
    const float* b1 = (const float*)d_in[11];
    const float* W2 = (const float*)d_in[12];
    const float* b2 = (const float*)d_in[13];
    float* out = (float*)d_out;
    float* ws  = (float*)d_ws;   // needs NWP*4 = 23.6 KB

    const int B = in_sizes[0] / 160;   // 65536
    prep_kernel<<<23, 256, 0, stream>>>(Ws, bs, Wq, bq, W1, b1, W2, b2, ws);
    fused_kernel<<<B / 128, 256, 0, stream>>>(scene, query, ws, out);
}

// Round 9
// 25.537 us; speedup vs baseline: 2.0017x; 1.0186x over previous
//
#include <hip/hip_runtime.h>

// ThetaGammaCLEVRN — MFMA, occupancy-tuned (R9).
// Math reduction (phase network dead; theta amps == 1):
//   sf[16] = sum_o scene[e,o,:]
//   x[g]   = sf@(0.1*Ws) + bs ; ga[g] = F20(sigmoid(x)) via 512-entry LUT
//   h      = relu(W @ act), W = [W1g | Weff | beff] (64x125), act = [ga;q;1]
//   out    = log_softmax(h @ W2 + b2)
// R9 over R8: single 64-element group per block (LDS 34.8 KB -> 4 blocks/CU)
// and __launch_bounds__(256,4) (4 waves/EU -> VGPR<=128, 16 waves/CU) —
// R8 ran at only 2 blocks/CU, leaving the serial stage->sync->compute chain
// latency-exposed. Const staging stays async gload_lds w/ swizzled source.

typedef __fp16 h2_t  __attribute__((ext_vector_type(2)));
typedef __fp16 f16x8 __attribute__((ext_vector_type(8)));
typedef float  f32x4 __attribute__((ext_vector_type(4)));
typedef unsigned u32x4 __attribute__((ext_vector_type(4)));

union H2U { unsigned u; h2_t h; };
union F8  { u32x4 u; f16x8 h; };

__device__ __forceinline__ unsigned pk(float a, float b) {
    H2U v; v.h = __builtin_amdgcn_cvt_pkrtz(a, b);
    return v.u;
}
__device__ __forceinline__ h2_t uh(unsigned x) { H2U v; v.u = x; return v.h; }
__device__ __forceinline__ float dot2(h2_t a, h2_t b, float c) {
    return __builtin_amdgcn_fdot2(a, b, c, false);
}
__device__ __forceinline__ float F20(float g) {
    #pragma unroll
    for (int n = 0; n < 20; ++n) {
        float g2 = g * g;
        g = fmaf(0.01f, g * (1.0f - g2), g);
    }
    return g;
}

// ws layout (u32/f32 words):
//   0    : Wh   [64][64] fp16 pairs, row j: (Wstack[2p][j], Wstack[2p+1][j])
//   4096 : ws2T [8][64]  fp16 pairs (0.1*Ws[2dp][g], 0.1*Ws[2dp+1][g])
//   4608 : LUT  [512]x2  (F(x_i), F(x_{i+1})-F(x_i)), x_i = i/64 - 4
//   5632 : bs   [64] f32
//   5696 : w2   [128] f32 (W2 row-major)
//   5824 : b2   [2] f32 ; pad zeros to 5888
#define NWP 5888

__global__ void prep_kernel(const float* __restrict__ Ws,
                            const float* __restrict__ bs,
                            const float* __restrict__ Wq,
                            const float* __restrict__ bq,
                            const float* __restrict__ W1,
                            const float* __restrict__ b1,
                            const float* __restrict__ W2,
                            const float* __restrict__ b2,
                            float* __restrict__ ws) {
    unsigned* wsu = (unsigned*)ws;
    int gid = blockIdx.x * 256 + threadIdx.x;
    if (gid < 4096) {                         // Wh pairs
        int j = gid >> 6, p = gid & 63;
        int k0 = 2 * p;
        float va = 0.f, vb = 0.f;
        if (p < 32) {
            va = W1[(16 + k0) * 64 + j];
            vb = W1[(17 + k0) * 64 + j];
        } else if (p < 62) {                  // Weff dims d0,d0+1
            int d0 = k0 - 64;
            float s0 = 0.f, s1 = 0.f;
            #pragma unroll 16
            for (int c = 0; c < 64; ++c) {
                float w = W1[(80 + c) * 64 + j];
                s0 = fmaf(Wq[d0 * 64 + c], w, s0);
                s1 = fmaf(Wq[(d0 + 1) * 64 + c], w, s1);
            }
            va = s0; vb = s1;
        } else if (p == 62) {                 // k=124: beff ; k=125: 0
            float acc = b1[j];
            #pragma unroll
            for (int r = 0; r < 16; ++r) acc += W1[r * 64 + j];
            #pragma unroll 16
            for (int c = 0; c < 64; ++c)
                acc = fmaf(bq[c], W1[(80 + c) * 64 + j], acc);
            va = acc; vb = 0.f;
        }
        wsu[gid] = pk(va, vb);
    } else if (gid < 4608) {                  // ws2T
        int w = gid - 4096, dp = w >> 6, g = w & 63;
        wsu[gid] = pk(0.1f * Ws[(2 * dp) * 64 + g],
                      0.1f * Ws[(2 * dp + 1) * 64 + g]);
    } else if (gid < 5632) {                  // LUT
        int li = gid - 4608, i = li >> 1;
        float x0 = (float)i * 0.015625f - 4.0f;
        float F0 = F20(1.0f / (1.0f + expf(-x0)));
        if (li & 1) {
            float F1 = F20(1.0f / (1.0f + expf(-(x0 + 0.015625f))));
            ws[gid] = F1 - F0;
        } else {
            ws[gid] = F0;
        }
    } else if (gid < 5696) {                  // bs
        ws[gid] = bs[gid - 5632];
    } else if (gid < 5824) {                  // W2 flat copy
        ws[gid] = W2[gid - 5696];
    } else if (gid < NWP) {
        ws[gid] = (gid == 5824) ? b2[0] : (gid == 5825) ? b2[1] : 0.f;
    }
}

// LDS word offsets (const block)
#define W0o  0
#define WS2o 4096
#define LUTo 4608
#define BSo  5632
#define W2o  5696
// activation buffer: sfT[8][64] at 0, qT[32][72] at 512
#define QP   72
#define ACTW 2816

__global__ __launch_bounds__(256, 4) void fused_kernel(
    const float* __restrict__ scene,   // (B,10,16)
    const float* __restrict__ query,   // (B,60)
    const float* __restrict__ wsbuf,   // NWP words
    float* __restrict__ out)           // (B,2)
{
    __shared__ unsigned lds[NWP];      // 23.0 KB constants
    __shared__ unsigned actS[ACTW];    // 11.3 KB activations

    const int t    = threadIdx.x;
    const int lane = t & 63;
    const int wv   = __builtin_amdgcn_readfirstlane(t) >> 6;   // SGPR wave id
    const int eb   = blockIdx.x << 6;      // 64 elements per block
    const unsigned* wsu = (const unsigned*)wsbuf;

    // ---- 1) async const staging: 23 chunks x 1 KB, swizzled SOURCE ----
    #pragma unroll
    for (int i = 0; i < 6; ++i) {
        const int chunk = wv * 6 + i;
        if (chunk < 23) {
            const int widx = (chunk << 8) | (lane << 2);
            const int src  = (widx < 4096) ? (widx ^ (((widx >> 6) & 7) << 2))
                                           : widx;
            __builtin_amdgcn_global_load_lds(
                (const __attribute__((address_space(1))) unsigned*)(wsu + src),
                (__attribute__((address_space(3))) unsigned*)&lds[chunk << 8],
                16, 0, 0);
        }
    }

    const int sel = t >> 2, q4 = t & 3;
    // ---- 2) scene: object-sum -> transposed fp16 pairs sfT[8][64] ----
    {
        const float4* sp = (const float4*)scene + (size_t)(eb + sel) * 40 + q4;
        float4 a = sp[0];
        #pragma unroll
        for (int o = 1; o < 10; ++o) {
            float4 v = sp[4 * o];
            a.x += v.x; a.y += v.y; a.z += v.z; a.w += v.w;
        }
        actS[((q4 << 1) + 0) * 64 + sel] = pk(a.x, a.y);
        actS[((q4 << 1) + 1) * 64 + sel] = pk(a.z, a.w);
    }
    // ---- 3) query -> transposed fp16 pairs qT[32][72] ----
    #pragma unroll
    for (int i = 0; i < 4; ++i) {
        const int idx = t + (i << 8);
        if (idx < 960) {
            const int qel = idx / 15, kq = idx - qel * 15;
            float4 qv = ((const float4*)query)[(size_t)(eb + qel) * 15 + kq];
            actS[512 + (2 * kq + 0) * QP + qel] = pk(qv.x, qv.y);
            actS[512 + (2 * kq + 1) * QP + qel] = pk(qv.z, qv.w);
        }
    }
    // ---- 4) pad rows: k=124 const-1 (beff), k=125..127 zero ----
    if (t < 64)       actS[512 + 30 * QP + t]        = pk(1.0f, 0.0f);
    else if (t < 128) actS[512 + 31 * QP + (t - 64)] = 0u;

    __syncthreads();   // consts + activations ready (drains gload_lds)

    // ============ compute: wave owns 16 elements (one MFMA N-tile) ========
    const int kb  = lane >> 4;
    const int elb = ((t >> 6) << 4) | (lane & 15);

    unsigned sf2[8];
    #pragma unroll
    for (int dp = 0; dp < 8; ++dp) sf2[dp] = actS[dp * 64 + elb];

    F8 bfrag[4];
    // ---- gamma B-frags c=0,1: x via dot2, then LUT, pack fp16 ----
    #pragma unroll
    for (int c = 0; c < 2; ++c) {
        float g[8];
        #pragma unroll
        for (int s = 0; s < 2; ++s) {
            unsigned wqa[8][4];
            #pragma unroll
            for (int dp = 0; dp < 8; ++dp) {
                u32x4 w = *(const u32x4*)&lds[WS2o + dp * 64 + (c << 5) + (kb << 3) + (s << 2)];
                wqa[dp][0] = w[0]; wqa[dp][1] = w[1];
                wqa[dp][2] = w[2]; wqa[dp][3] = w[3];
            }
            #pragma unroll
            for (int i2 = 0; i2 < 4; ++i2) {
                float x = __uint_as_float(lds[BSo + (c << 5) + (kb << 3) + (s << 2) + i2]);
                #pragma unroll
                for (int dp = 0; dp < 8; ++dp)
                    x = dot2(uh(sf2[dp]), uh(wqa[dp][i2]), x);
                float u = fminf(fmaxf(fmaf(x, 64.0f, 256.0f), 0.0f), 511.0f);
                int   i0 = (int)u;
                float2 e = *(const float2*)&lds[LUTo + (i0 << 1)];
                g[(s << 2) + i2] = fmaf(u - (float)i0, e.y, e.x);
            }
        }
        F8 f;
        f.u[0] = pk(g[0], g[1]); f.u[1] = pk(g[2], g[3]);
        f.u[2] = pk(g[4], g[5]); f.u[3] = pk(g[6], g[7]);
        bfrag[c] = f;
    }
    // ---- query B-frags c=2,3 (includes the const-1 beff column) ----
    #pragma unroll
    for (int c2 = 0; c2 < 2; ++c2) {
        F8 f;
        #pragma unroll
        for (int r = 0; r < 4; ++r)
            f.u[r] = actS[512 + ((kb << 2) + r + (c2 << 4)) * QP + elb];
        bfrag[2 + c2] = f;
    }

    // ---- MFMA: 4 j-tiles x 4 k-chunks; fused epilogue per j-tile ----
    float l0 = 0.f, l1 = 0.f;
    #pragma unroll
    for (int jt = 0; jt < 4; ++jt) {
        f32x4 acc = {0.f, 0.f, 0.f, 0.f};
        const int j = (jt << 4) | (lane & 15);
        #pragma unroll
        for (int c = 0; c < 4; ++c) {
            const int ch = ((c << 2) | kb) ^ (j & 7);
            F8 a;
            a.u = *(const u32x4*)&lds[W0o + (j << 6) + (ch << 2)];
            acc = __builtin_amdgcn_mfma_f32_16x16x32_f16(a.h, bfrag[c].h, acc, 0, 0, 0);
        }
        #pragma unroll
        for (int r = 0; r < 4; ++r) {
            const int jr = (jt << 4) + (kb << 2) + r;
            float hv = fmaxf(acc[r], 0.f);
            float2 wv2 = *(const float2*)&lds[W2o + (jr << 1)];
            l0 = fmaf(hv, wv2.x, l0);
            l1 = fmaf(hv, wv2.y, l1);
        }
    }
    // ---- reduce over k-groups, log_softmax, store ----
    l0 += __shfl_xor(l0, 16); l0 += __shfl_xor(l0, 32);
    l1 += __shfl_xor(l1, 16); l1 += __shfl_xor(l1, 32);
    l0 += wsbuf[5824]; l1 += wsbuf[5825];
    if (lane < 16) {
        const float mx = fmaxf(l0, l1);
        const float lz = mx + __logf(__expf(l0 - mx) + __expf(l1 - mx));
        float2 o = { l0 - lz, l1 - lz };
        ((float2*)out)[eb + elb] = o;
    }
}

extern "C" void kernel_launch(void* const* d_in, const int* in_sizes, int n_in,
                              void* d_out, int out_size, void* d_ws, size_t ws_size,
                              hipStream_t stream) {
    const float* scene = (const float*)d_in[0];
    const float* query = (const float*)d_in[1];
    // d_in[2..5] = theta/gamma phase & freq: provably unused by the output
    const float* Ws = (const float*)d_in[6];
    const float* bs = (const float*)d_in[7];
    const float* Wq = (const float*)d_in[8];
    const float* bq = (const float*)d_in[9];
    const float* W1 = (const float*)d_in[10];
    const float* b1 = (const float*)d_in[11];
    const float* W2 = (const float*)d_in[12];
    const float* b2 = (const float*)d_in[13];
    float* out = (float*)d_out;
    float* ws  = (float*)d_ws;   // needs NWP*4 = 23.6 KB

    const int B = in_sizes[0] / 160;   // 65536
    prep_kernel<<<23, 256, 0, stream>>>(Ws, bs, Wq, bq, W1, b1, W2, b2, ws);
    fused_kernel<<<B / 64, 256, 0, stream>>>(scene, query, ws, out);
}